// Round 1
// 795.252 us; speedup vs baseline: 1.1309x; 1.1309x over previous
//
#include <hip/hip_runtime.h>
#include <hip/hip_bf16.h>
#include <cstdint>
#include <math.h>

// ---------------------------------------------------------------------------
// MultiHeadAttention: B=512, T=128, D=768, H=12, hd=64. fp32 in/out,
// bf16 MFMA compute.
//
// Stages:
//   1) cast x (fp32) -> bf16                     [M=65536 x 768]
//   2) transpose+cast Wq/Wk/Wv -> Wqkv^T bf16    [2304 x 768], Wo^T [768 x 768]
//   3) GEMM qkv = x * Wqkv   (bf16 out)          [65536 x 2304]   gemm256
//   4) attention per (b,h); ctx overwrites Q region of qkv
//   5) GEMM out = ctx * Wo + bo (fp32 out)                        gemm256
//
// gemm256: 256x256 tile, BK=32, 8 waves, 4-deep K-tile LDS ring (128 KiB),
// counted vmcnt(8) across raw s_barrier (T3/T4), XOR-swizzled LDS (T2),
// setprio around MFMA cluster (T5), A-panel-major + XCD block swizzle (T1).
// ---------------------------------------------------------------------------

typedef __bf16 bf16;
typedef __bf16 bf16x8 __attribute__((ext_vector_type(8)));
typedef float f32x4 __attribute__((ext_vector_type(4)));

#define MFMA16(a, b, c) __builtin_amdgcn_mfma_f32_16x16x32_bf16((a), (b), (c), 0, 0, 0)

// async global->LDS, 16B per lane; LDS dest = wave-uniform base + lane*16
#define GLD_LDS16(gp, lp)                                                       \
  __builtin_amdgcn_global_load_lds(                                             \
      (const __attribute__((address_space(1))) void*)(gp),                      \
      (__attribute__((address_space(3))) void*)(lp), 16, 0, 0)

// ---------------------------------------------------------------------------
// Stage 1: fp32 -> bf16 cast, 4 elems/thread
// ---------------------------------------------------------------------------
__global__ __launch_bounds__(256) void cast_x_bf16(const float* __restrict__ in,
                                                   bf16* __restrict__ out, int n) {
  int i = (blockIdx.x * 256 + threadIdx.x) * 4;
  if (i < n) {
    float4 v = *(const float4*)(in + i);
    bf16 o[4] = {(bf16)v.x, (bf16)v.y, (bf16)v.z, (bf16)v.w};
    *(uint2*)(out + i) = *(const uint2*)o;
  }
}

// ---------------------------------------------------------------------------
// Stage 2: 768x768 transpose + cast: Out[n][k] = W[k][n]
// ---------------------------------------------------------------------------
__global__ __launch_bounds__(256) void transpose_cast_w(const float* __restrict__ W,
                                                        bf16* __restrict__ Out) {
  __shared__ float t[32][33];
  int bx = blockIdx.x * 32;  // k tile
  int by = blockIdx.y * 32;  // n tile
  int tx = threadIdx.x, ty = threadIdx.y;  // block (32,8)
  for (int i = 0; i < 32; i += 8)
    t[ty + i][tx] = W[(size_t)(bx + ty + i) * 768 + by + tx];
  __syncthreads();
  for (int i = 0; i < 32; i += 8)
    Out[(size_t)(by + ty + i) * 768 + bx + tx] = (bf16)t[tx][ty + i];
}

// ---------------------------------------------------------------------------
// Stages 3/5: bf16 GEMM, C[M,N] = A[M,K] * Bt[N,K]^T.
// Requires M%256==0, N%256==0, K%32==0, K>=96, gridDim.x%8==0.
//
// LDS ring: 4 bufs x (A[256][32] + B[256][32]) bf16 = 4 x 32 KiB.
// Swizzle (involution, bits 4-5 ^= row bits 1-2):
//   phys_byte = logical_byte ^ (((logical_byte>>7)&3)<<4)
// Applied on BOTH the staging source (pre-swizzled global address, linear
// gload_lds dest) and the fragment read address; reduces the 8-way
// ds_read_b128 conflict to a free 2-way.
//
// Pipeline invariant at loop-top barrier for iteration t:
//   - tile t fully in LDS (vmcnt counted wait last iter drained its 4 loads)
//   - tiles t+1, t+2 in flight (<= 8 loads outstanding per wave)
//   - buf (t+3)&3 free: its occupant (tile t-1) was fully read before the
//     previous barrier (compiler lgkmcnt precedes each consuming MFMA).
// => staging tile t+3 during iteration t is race-free; vmcnt is never 0 in
//    the steady-state loop (T4).
// ---------------------------------------------------------------------------
template <bool OUT_F32>
__global__ __launch_bounds__(512, 2) void gemm256(
    const bf16* __restrict__ A, int lda, const bf16* __restrict__ Bt, int ldb,
    void* __restrict__ Cout, int ldc, const float* __restrict__ bias, int K,
    int ntn) {
  __shared__ bf16 smem[4 * 16384];  // 131072 B

  const int tid = threadIdx.x;
  const int lane = tid & 63;
  const int w = tid >> 6;

  // T1: nt-major within A-panel groups (ntn consecutive wg share an A-panel),
  // XCD-chunked bijective swizzle (gridDim.x % 8 == 0).
  const int nwg = gridDim.x;
  const int wg = (blockIdx.x & 7) * (nwg >> 3) + (blockIdx.x >> 3);
  const int m0 = (wg / ntn) * 256;
  const int n0 = (wg % ntn) * 256;

  // Staging constants. Linear dest byte d = s*8192 + tid*16 within a 16 KiB
  // region; stored logical byte l = d ^ (((d>>7)&3)<<4). Per-thread constant:
  const int r0 = tid >> 2;                                           // row 0..127
  const int c0 = ((((tid & 3) * 16) ^ (((tid >> 3) & 3) << 4)) >> 1);  // elem col
  const bf16* Ablk = A + (size_t)m0 * lda;
  const bf16* Bblk = Bt + (size_t)n0 * ldb;

  // Fragment-read constants; swizzle XOR depends only on lane (row bits 1-2
  // come from lm since wm/wn/mi*16 don't touch bits 1-2).
  const int lm = lane & 15;
  const int kqs = ((lane >> 4) * 8) ^ (((lm >> 1) & 3) << 3);  // elems
  const int wm = (w & 1) * 128;   // wave M-group: rows 0-127 / 128-255
  const int wn = (w >> 1) * 64;   // wave N-group: 4 x 64 cols

  f32x4 acc[8][4];
#pragma unroll
  for (int i = 0; i < 8; ++i)
#pragma unroll
    for (int j = 0; j < 4; ++j) acc[i][j] = (f32x4){0.f, 0.f, 0.f, 0.f};

  const int NT = K >> 5;  // 24 for K=768

#define STAGE(t)                                                                  \
  {                                                                               \
    bf16* sb = smem + ((t) & 3) * 16384;                                          \
    const int k0 = (t) * 32;                                                      \
    GLD_LDS16(Ablk + (size_t)r0 * lda + k0 + c0, sb + w * 512);                   \
    GLD_LDS16(Ablk + (size_t)(128 + r0) * lda + k0 + c0, sb + 4096 + w * 512);    \
    GLD_LDS16(Bblk + (size_t)r0 * ldb + k0 + c0, sb + 8192 + w * 512);            \
    GLD_LDS16(Bblk + (size_t)(128 + r0) * ldb + k0 + c0, sb + 12288 + w * 512);   \
  }

  // prologue: tiles 0..2 in flight, wait tile 0 (8 = loads of tiles 1,2 remain)
  STAGE(0);
  STAGE(1);
  STAGE(2);
  asm volatile("s_waitcnt vmcnt(8)" ::: "memory");
  __builtin_amdgcn_s_barrier();
  __builtin_amdgcn_sched_barrier(0);

  for (int t = 0; t < NT; ++t) {
    if (t + 3 < NT) STAGE(t + 3);

    const bf16* base = smem + (t & 3) * 16384;
    bf16x8 af[8], bfr[4];
#pragma unroll
    for (int mi = 0; mi < 8; ++mi)
      af[mi] = *(const bf16x8*)(base + (wm + mi * 16 + lm) * 32 + kqs);
#pragma unroll
    for (int ni = 0; ni < 4; ++ni)
      bfr[ni] = *(const bf16x8*)(base + 8192 + (wn + ni * 16 + lm) * 32 + kqs);

    __builtin_amdgcn_s_setprio(1);
#pragma unroll
    for (int mi = 0; mi < 8; ++mi)
#pragma unroll
      for (int ni = 0; ni < 4; ++ni)
        acc[mi][ni] = MFMA16(af[mi], bfr[ni], acc[mi][ni]);
    __builtin_amdgcn_s_setprio(0);

    // counted wait: tile t+1 must be complete; loads younger than it are the
    // stages of tiles t+2 / t+3 (4 each, if they exist).
    if (t + 3 < NT)
      asm volatile("s_waitcnt vmcnt(8)" ::: "memory");
    else if (t + 3 == NT)
      asm volatile("s_waitcnt vmcnt(4)" ::: "memory");
    else
      asm volatile("s_waitcnt vmcnt(0)" ::: "memory");
    __builtin_amdgcn_s_barrier();
    __builtin_amdgcn_sched_barrier(0);
  }
#undef STAGE

  // epilogue: C/D layout col=lane&15, row=(lane>>4)*4+reg  [m89/m91]
  const int lr = (lane >> 4) * 4;
#pragma unroll
  for (int mi = 0; mi < 8; ++mi)
#pragma unroll
    for (int ni = 0; ni < 4; ++ni) {
      const int col = n0 + wn + ni * 16 + lm;
#pragma unroll
      for (int r = 0; r < 4; ++r) {
        const int row = m0 + wm + mi * 16 + lr + r;
        if constexpr (OUT_F32)
          ((float*)Cout)[(size_t)row * ldc + col] = acc[mi][ni][r] + bias[col];
        else
          ((bf16*)Cout)[(size_t)row * ldc + col] = (bf16)acc[mi][ni][r];
      }
    }
}

// ---------------------------------------------------------------------------
// Stage 4: attention, one block (256 thr, 4 waves) per (b,h). Unchanged.
// ---------------------------------------------------------------------------
__global__ __launch_bounds__(256) void attn_kernel(const bf16* __restrict__ qkv,
                                                   bf16* __restrict__ ctx) {
  constexpr int LDQ = 2304;
  constexpr int SQS = 72;   // sQ/sK row stride (64 cols + pad)
  constexpr int SPS = 136;  // sP/sVt row stride (128 cols + pad)
  __shared__ bf16 smem[27136];              // 54272 B
  bf16* sQ = smem;                          // [128][72]
  bf16* sK = smem + 128 * SQS;              // [128][72]
  bf16* sVt = smem + 2 * 128 * SQS;         // [64][136]  Vt[d][t] = V[t][d]
  bf16* sP = smem;                          // [128][136] aliases sQ+sK

  const int bh = blockIdx.x;
  const int b = bh / 12, h = bh % 12;
  const bf16* Qg = qkv + (size_t)b * 128 * LDQ + h * 64;
  const bf16* Kg = Qg + 768;
  const bf16* Vg = Qg + 1536;

  const int tid = threadIdx.x;
  // ---- load Q,K row-major; V transposed ----
  {
    int row = tid >> 1, half = tid & 1;
    const uint4* qsrc = (const uint4*)(Qg + (size_t)row * LDQ + half * 32);
    const uint4* ksrc = (const uint4*)(Kg + (size_t)row * LDQ + half * 32);
    const uint4* vsrc = (const uint4*)(Vg + (size_t)row * LDQ + half * 32);
    uint4* qdst = (uint4*)(sQ + row * SQS + half * 32);
    uint4* kdst = (uint4*)(sK + row * SQS + half * 32);
    uint4 vt[4];
    for (int i = 0; i < 4; ++i) {
      qdst[i] = qsrc[i];
      kdst[i] = ksrc[i];
      vt[i] = vsrc[i];
    }
    const bf16* tp = (const bf16*)vt;
    for (int d = 0; d < 32; ++d) sVt[(half * 32 + d) * SPS + row] = tp[d];
  }
  __syncthreads();

  const int lane = tid & 63;
  const int w = tid >> 6;      // wave handles rows w*32 .. w*32+31
  const int lm = lane & 15;
  const int kq = (lane >> 4) * 8;
  const int lr = (lane >> 4) * 4;

  // ---- S = Q K^T : 2 row-subtiles x 8 col-subtiles per wave ----
  f32x4 sacc[2][8];
  for (int i = 0; i < 2; ++i)
    for (int j = 0; j < 8; ++j) sacc[i][j] = (f32x4){0.f, 0.f, 0.f, 0.f};
  for (int kk = 0; kk < 64; kk += 32) {
    bf16x8 aq[2], bk[8];
    for (int mi = 0; mi < 2; ++mi)
      aq[mi] = *(const bf16x8*)(sQ + (w * 32 + mi * 16 + lm) * SQS + kk + kq);
    for (int ni = 0; ni < 8; ++ni)
      bk[ni] = *(const bf16x8*)(sK + (ni * 16 + lm) * SQS + kk + kq);
    for (int mi = 0; mi < 2; ++mi)
      for (int ni = 0; ni < 8; ++ni)
        sacc[mi][ni] = MFMA16(aq[mi], bk[ni], sacc[mi][ni]);
  }

  // ---- causal softmax (scale=1/8) ----
  float inv[2][4];
  for (int mi = 0; mi < 2; ++mi) {
    for (int r = 0; r < 4; ++r) {
      int row = w * 32 + mi * 16 + lr + r;
      float vals[8];
      float mx = -INFINITY;
      for (int ni = 0; ni < 8; ++ni) {
        int col = ni * 16 + lm;
        float v = sacc[mi][ni][r] * 0.125f;
        if (col > row) v = -INFINITY;
        vals[ni] = v;
        mx = fmaxf(mx, v);
      }
      for (int off = 1; off < 16; off <<= 1) mx = fmaxf(mx, __shfl_xor(mx, off, 64));
      float sum = 0.f;
      for (int ni = 0; ni < 8; ++ni) {
        float p = __expf(vals[ni] - mx);  // exp(-inf)=0
        vals[ni] = p;
        sum += p;
      }
      for (int off = 1; off < 16; off <<= 1) sum += __shfl_xor(sum, off, 64);
      inv[mi][r] = 1.f / sum;
      for (int ni = 0; ni < 8; ++ni) sacc[mi][ni][r] = vals[ni];
    }
  }
  __syncthreads();  // all waves done reading sQ/sK before sP overwrites them

  // ---- write unnormalized P (bf16) to LDS ----
  for (int mi = 0; mi < 2; ++mi)
    for (int ni = 0; ni < 8; ++ni)
      for (int r = 0; r < 4; ++r) {
        int row = w * 32 + mi * 16 + lr + r;
        int col = ni * 16 + lm;
        sP[row * SPS + col] = (bf16)sacc[mi][ni][r];
      }
  __syncthreads();

  // ---- ctx = P * V ----
  f32x4 oacc[2][4];
  for (int i = 0; i < 2; ++i)
    for (int j = 0; j < 4; ++j) oacc[i][j] = (f32x4){0.f, 0.f, 0.f, 0.f};
  for (int kk = 0; kk < 128; kk += 32) {
    bf16x8 ap[2], bv[4];
    for (int mi = 0; mi < 2; ++mi)
      ap[mi] = *(const bf16x8*)(sP + (w * 32 + mi * 16 + lm) * SPS + kk + kq);
    for (int ci = 0; ci < 4; ++ci)
      bv[ci] = *(const bf16x8*)(sVt + (ci * 16 + lm) * SPS + kk + kq);
    for (int mi = 0; mi < 2; ++mi)
      for (int ci = 0; ci < 4; ++ci)
        oacc[mi][ci] = MFMA16(ap[mi], bv[ci], oacc[mi][ci]);
  }

  // ---- write ctx over the Q region ----
  bf16* Cg = ctx + (size_t)b * 128 * LDQ + h * 64;
  for (int mi = 0; mi < 2; ++mi)
    for (int ci = 0; ci < 4; ++ci)
      for (int r = 0; r < 4; ++r) {
        int row = w * 32 + mi * 16 + lr + r;
        int col = ci * 16 + lm;
        Cg[(size_t)row * LDQ + col] = (bf16)(oacc[mi][ci][r] * inv[mi][r]);
      }
}

// ---------------------------------------------------------------------------
extern "C" void kernel_launch(void* const* d_in, const int* in_sizes, int n_in,
                              void* d_out, int out_size, void* d_ws, size_t ws_size,
                              hipStream_t stream) {
  const float* x = (const float*)d_in[0];
  const float* Wq = (const float*)d_in[1];
  const float* Wk = (const float*)d_in[2];
  const float* Wv = (const float*)d_in[3];
  const float* Wo = (const float*)d_in[4];
  const float* bo = (const float*)d_in[5];
  float* out = (float*)d_out;

  constexpr int M = 512 * 128;      // 65536 tokens
  constexpr int D = 768;
  constexpr size_t XB_BYTES = (size_t)M * D * 2;            // 100663296
  constexpr size_t WQKV_BYTES = (size_t)3 * D * D * 2;      // 3538944
  constexpr size_t WOT_BYTES = (size_t)D * D * 2;           // 1179648

  char* ws = (char*)d_ws;
  bf16* xb = (bf16*)ws;
  bf16* wqkv = (bf16*)(ws + XB_BYTES);
  bf16* wot = (bf16*)(ws + XB_BYTES + WQKV_BYTES);
  bf16* qkv = (bf16*)(ws + XB_BYTES + WQKV_BYTES + WOT_BYTES);  // [M][2304]

  // 1) cast x
  cast_x_bf16<<<(M * D) / 1024, 256, 0, stream>>>(x, xb, M * D);
  // 2) weight transposes
  dim3 tb(32, 8);
  transpose_cast_w<<<dim3(24, 24), tb, 0, stream>>>(Wq, wqkv);
  transpose_cast_w<<<dim3(24, 24), tb, 0, stream>>>(Wk, wqkv + 768 * 768);
  transpose_cast_w<<<dim3(24, 24), tb, 0, stream>>>(Wv, wqkv + 2 * 768 * 768);
  transpose_cast_w<<<dim3(24, 24), tb, 0, stream>>>(Wo, wot);
  // 3) fused QKV GEMM: [65536 x 768] * [768 x 2304] -> bf16 [65536 x 2304]
  //    grid = 256 M-tiles x 9 N-tiles = 2304 (divisible by 8)
  gemm256<false><<<dim3(2304), 512, 0, stream>>>(xb, 768, wqkv, 768, qkv, 2304,
                                                 nullptr, 768, 9);
  // 4) attention; ctx written in-place over Q region of qkv
  attn_kernel<<<512 * 12, 256, 0, stream>>>(qkv, qkv);
  // 5) output GEMM: ctx [65536 x 768] (lda=2304) * Wo -> fp32 out + bias
  //    grid = 256 M-tiles x 3 N-tiles = 768 (divisible by 8)
  gemm256<true><<<dim3(768), 512, 0, stream>>>(qkv, 2304, wot, 768, out, 768,
                                               bo, 768, 3);
}

// Round 2
// 788.794 us; speedup vs baseline: 1.1402x; 1.0082x over previous
//
#include <hip/hip_runtime.h>
#include <hip/hip_bf16.h>
#include <cstdint>
#include <math.h>

// ---------------------------------------------------------------------------
// MultiHeadAttention: B=512, T=128, D=768, H=12, hd=64. fp32 in/out,
// bf16 MFMA compute.
//
// Stages:
//   1) cast x (fp32) -> bf16                     [M=65536 x 768]
//   2) transpose+cast Wq/Wk/Wv -> Wqkv^T bf16    [2304 x 768], Wo^T [768 x 768]
//   3) GEMM qkv = x * Wqkv   (bf16 out)          [65536 x 2304]   gemm256
//   4) attention per (b,h); ctx overwrites Q region of qkv
//   5) GEMM out = ctx * Wo + bo (fp32 out)                        gemm256
//
// gemm256 (this round): 8-phase schedule (m201-style, T3+T4+T5+T2+T1):
// 256x256 tile, BK=64, 8 waves (2M x 4N), 2-buffer LDS of 4 x 16KiB panels
// per buffer {A_k0, A_k1, B_k0, B_k1}. Per phase: {ds_read frag subtile,
// stage one half-tile via global_load_lds, (vmcnt(6) at phases 4/8),
// s_barrier, lgkmcnt(0), sched_barrier, setprio(1), 16 MFMA, setprio(0),
// s_barrier}. Counted vmcnt never drains to 0 in steady state.
//
// Staging legality ledger (phases of one iteration, tiles 2i/buf0, 2i+1/buf1):
//   region read-completion:  buf0.B_k0 end-ph1, A_k0 end-ph2, B_k1 end-ph3,
//                            A_k1 end-ph4; buf1 mirrored at ph5..ph8.
//   stage schedule (always targets a region freed the previous phase):
//     ph1: A_k1(t2i+1)->buf1   ph2: B_k0(t2i+2)->buf0  ph3: A_k0(t2i+2)
//     ph4: B_k1(t2i+2) +vm6    ph5: A_k1(t2i+2)        ph6: B_k0(t2i+3)->buf1
//     ph7: A_k0(t2i+3)         ph8: B_k1(t2i+3) +vm6
//   vmcnt(6)+barrier at ph4/ph8 => all stages >=3 phases old have landed =>
//   tile 2i+1 complete before ph5, tile 2i+2 complete before next ph1.
//   Last iteration peeled: stage only A_k1(NT-1) at ph1, vmcnt(0) at ph4.
// ---------------------------------------------------------------------------

typedef __bf16 bf16;
typedef __bf16 bf16x8 __attribute__((ext_vector_type(8)));
typedef float f32x4 __attribute__((ext_vector_type(4)));

#define MFMA16(a, b, c) __builtin_amdgcn_mfma_f32_16x16x32_bf16((a), (b), (c), 0, 0, 0)

// async global->LDS, 16B per lane; LDS dest = wave-uniform base + lane*16
#define GLD_LDS16(gp, lp)                                                       \
  __builtin_amdgcn_global_load_lds(                                             \
      (const __attribute__((address_space(1))) void*)(gp),                      \
      (__attribute__((address_space(3))) void*)(lp), 16, 0, 0)

// ---------------------------------------------------------------------------
// Stage 1: fp32 -> bf16 cast, 4 elems/thread
// ---------------------------------------------------------------------------
__global__ __launch_bounds__(256) void cast_x_bf16(const float* __restrict__ in,
                                                   bf16* __restrict__ out, int n) {
  int i = (blockIdx.x * 256 + threadIdx.x) * 4;
  if (i < n) {
    float4 v = *(const float4*)(in + i);
    bf16 o[4] = {(bf16)v.x, (bf16)v.y, (bf16)v.z, (bf16)v.w};
    *(uint2*)(out + i) = *(const uint2*)o;
  }
}

// ---------------------------------------------------------------------------
// Stage 2: 768x768 transpose + cast: Out[n][k] = W[k][n]
// ---------------------------------------------------------------------------
__global__ __launch_bounds__(256) void transpose_cast_w(const float* __restrict__ W,
                                                        bf16* __restrict__ Out) {
  __shared__ float t[32][33];
  int bx = blockIdx.x * 32;  // k tile
  int by = blockIdx.y * 32;  // n tile
  int tx = threadIdx.x, ty = threadIdx.y;  // block (32,8)
  for (int i = 0; i < 32; i += 8)
    t[ty + i][tx] = W[(size_t)(bx + ty + i) * 768 + by + tx];
  __syncthreads();
  for (int i = 0; i < 32; i += 8)
    Out[(size_t)(by + ty + i) * 768 + bx + tx] = (bf16)t[tx][ty + i];
}

// ---------------------------------------------------------------------------
// Stages 3/5: bf16 GEMM, C[M,N] = A[M,K] * Bt[N,K]^T.
// Requires M%256==0, N%256==0, K%64==0, K/64 even and >=4, gridDim.x%8==0.
// ---------------------------------------------------------------------------
template <bool OUT_F32>
__global__ __launch_bounds__(512, 2) void gemm256(
    const bf16* __restrict__ A, int lda, const bf16* __restrict__ Bt, int ldb,
    void* __restrict__ Cout, int ldc, const float* __restrict__ bias, int K,
    int ntn) {
  // 2 buffers x 32768 elems; per buffer panels (8192 elems = 16 KiB each):
  //   A_k0 @0, A_k1 @8192, B_k0 @16384, B_k1 @24576
  __shared__ bf16 smem[2 * 32768];  // 131072 B

  const int tid = threadIdx.x;
  const int lane = tid & 63;
  const int w = tid >> 6;

  // T1: nt-major within A-panel groups, XCD-chunked bijective swizzle.
  const int nwg = gridDim.x;
  const int wg = (blockIdx.x & 7) * (nwg >> 3) + (blockIdx.x >> 3);
  const int m0 = (wg / ntn) * 256;
  const int n0 = (wg % ntn) * 256;

  // Staging constants (verified round 1): per-panel [256 rows][32 k], rows at
  // 64 B stride, swizzle phys_byte = logical ^ (((logical>>7)&3)<<4).
  // Linear dest d = s*8192B + tid*16B -> row = s*128 + (tid>>2),
  // source col elems c0 = swizzled per-thread constant.
  const int r0 = tid >> 2;
  const int c0 = ((((tid & 3) * 16) ^ (((tid >> 3) & 3) << 4)) >> 1);
  const bf16* As0 = A + (size_t)(m0 + r0) * lda + c0;
  const bf16* As1 = As0 + (size_t)128 * lda;
  const bf16* Bs0 = Bt + (size_t)(n0 + r0) * ldb + c0;
  const bf16* Bs1 = Bs0 + (size_t)128 * ldb;

  // Fragment-read constants (same swizzle, row bits 1-2 == lm bits 1-2).
  const int lm = lane & 15;
  const int kqs = ((lane >> 4) * 8) ^ (((lm >> 1) & 3) << 3);
  const int wm = (w & 1) * 128;   // wave M rows
  const int wn = (w >> 1) * 64;   // wave N cols
  const bf16* pA = smem + (wm + lm) * 32 + kqs;
  const bf16* pB = smem + 16384 + (wn + lm) * 32 + kqs;

  f32x4 acc[8][4];
#pragma unroll
  for (int i = 0; i < 8; ++i)
#pragma unroll
    for (int j = 0; j < 4; ++j) acc[i][j] = (f32x4){0.f, 0.f, 0.f, 0.f};

  bf16x8 af[4], bfr[4];

  const int NT = K >> 6;   // K-tiles of 64; 12 for K=768
  const int NH = NT >> 1;  // main iterations

  // half-tile stagers: tile t, k-half kh
  auto SA = [&](int t, int kh) {
    const int ko = t * 64 + kh * 32;
    const int lo = (t & 1) * 32768 + kh * 8192;
    GLD_LDS16(As0 + ko, smem + lo + w * 512);
    GLD_LDS16(As1 + ko, smem + lo + 4096 + w * 512);
  };
  auto SB = [&](int t, int kh) {
    const int ko = t * 64 + kh * 32;
    const int lo = (t & 1) * 32768 + 16384 + kh * 8192;
    GLD_LDS16(Bs0 + ko, smem + lo + w * 512);
    GLD_LDS16(Bs1 + ko, smem + lo + 4096 + w * 512);
  };
  // fragment reads for phase (buf, kh, h); lo-phases also load all 4 B frags
  auto RD = [&](int buf, int kh, int h, bool lb) {
    const bf16* a = pA + buf * 32768 + kh * 8192 + h * 2048;
#pragma unroll
    for (int j = 0; j < 4; ++j) af[j] = *(const bf16x8*)(a + j * 512);
    if (lb) {
      const bf16* b = pB + buf * 32768 + kh * 8192;
#pragma unroll
      for (int j = 0; j < 4; ++j) bfr[j] = *(const bf16x8*)(b + j * 512);
    }
  };
  auto BARMID = [&](int vm) {
    if (vm == 6) asm volatile("s_waitcnt vmcnt(6)" ::: "memory");
    else if (vm == 0) asm volatile("s_waitcnt vmcnt(0)" ::: "memory");
    __builtin_amdgcn_s_barrier();
    asm volatile("s_waitcnt lgkmcnt(0)" ::: "memory");
    __builtin_amdgcn_sched_barrier(0);
  };
  auto BAREND = [&]() {
    __builtin_amdgcn_s_barrier();
    __builtin_amdgcn_sched_barrier(0);
  };
  auto MM = [&](int h) {
    __builtin_amdgcn_s_setprio(1);
#pragma unroll
    for (int j = 0; j < 4; ++j)
#pragma unroll
      for (int n = 0; n < 4; ++n)
        acc[h * 4 + j][n] = MFMA16(af[j], bfr[n], acc[h * 4 + j][n]);
    __builtin_amdgcn_s_setprio(0);
  };

  // ---- prologue: tile 0 fully + tile 1 minus A_k1 ----
  SB(0, 0); SA(0, 0); SB(0, 1); SA(0, 1);
  asm volatile("s_waitcnt vmcnt(4)" ::: "memory");
  SB(1, 0); SA(1, 0); SB(1, 1);
  asm volatile("s_waitcnt vmcnt(6)" ::: "memory");
  __builtin_amdgcn_s_barrier();
  __builtin_amdgcn_sched_barrier(0);

  // ---- main loop: iterations 0 .. NH-2 ----
  for (int i = 0; i < NH - 1; ++i) {
    const int t1 = 2 * i + 1, t2 = 2 * i + 2, t3 = 2 * i + 3;
    RD(0, 0, 0, true);  SA(t1, 1); BARMID(-1); MM(0); BAREND();  // ph1
    RD(0, 0, 1, false); SB(t2, 0); BARMID(-1); MM(1); BAREND();  // ph2
    RD(0, 1, 0, true);  SA(t2, 0); BARMID(-1); MM(0); BAREND();  // ph3
    RD(0, 1, 1, false); SB(t2, 1); BARMID(6);  MM(1); BAREND();  // ph4
    RD(1, 0, 0, true);  SA(t2, 1); BARMID(-1); MM(0); BAREND();  // ph5
    RD(1, 0, 1, false); SB(t3, 0); BARMID(-1); MM(1); BAREND();  // ph6
    RD(1, 1, 0, true);  SA(t3, 0); BARMID(-1); MM(0); BAREND();  // ph7
    RD(1, 1, 1, false); SB(t3, 1); BARMID(6);  MM(1); BAREND();  // ph8
  }
  // ---- last iteration (tiles NT-2, NT-1): only stage A_k1(NT-1) ----
  RD(0, 0, 0, true);  SA(NT - 1, 1); BARMID(-1); MM(0); BAREND();
  RD(0, 0, 1, false);                BARMID(-1); MM(1); BAREND();
  RD(0, 1, 0, true);                 BARMID(-1); MM(0); BAREND();
  RD(0, 1, 1, false);                BARMID(0);  MM(1); BAREND();
  RD(1, 0, 0, true);                 BARMID(-1); MM(0); BAREND();
  RD(1, 0, 1, false);                BARMID(-1); MM(1); BAREND();
  RD(1, 1, 0, true);                 BARMID(-1); MM(0); BAREND();
  RD(1, 1, 1, false);                BARMID(-1); MM(1); BAREND();

  __syncthreads();  // all staging landed (vmcnt(0) above), LDS free for epilogue

  // ---- vectorized epilogue via LDS ----
  // C/D layout: col=lane&15, row=(lane>>4)*4+reg  [m89/m91]
  const int lr = (lane >> 4) * 4;
  if constexpr (!OUT_F32) {
    // bf16 C-tile [256][256] in LDS (128 KiB). Write swizzle: XOR row bits
    // 2-3 (== lane>>4) into byte bits 5-6 -> the four 32B row-group segments
    // land in distinct slots (conflict-free).
    const unsigned exw = (unsigned)(lane >> 4) << 5;
#pragma unroll
    for (int mi = 0; mi < 8; ++mi)
#pragma unroll
      for (int ni = 0; ni < 4; ++ni) {
        const int colb = (wn + ni * 16 + lm) * 2;
#pragma unroll
        for (int r = 0; r < 4; ++r) {
          const unsigned ad = (unsigned)(wm + mi * 16 + lr + r) * 512 + colb;
          *(bf16*)((char*)smem + (ad ^ exw)) = (bf16)acc[mi][ni][r];
        }
      }
    __syncthreads();
    const unsigned exr = (unsigned)((tid >> 7) & 3) << 5;  // row bits 2-3
#pragma unroll
    for (int s = 0; s < 16; ++s) {
      const int e = s * 4096 + tid * 8;
      const int row = e >> 8, col = e & 255;
      uint4 v = *(const uint4*)((char*)smem + (((unsigned)row * 512 + col * 2) ^ exr));
      *(uint4*)((bf16*)Cout + (size_t)(m0 + row) * ldc + n0 + col) = v;
    }
  } else {
    // fp32 in two 128-row halves: [128][256] f32 = 128 KiB. XOR row bits 2-3
    // into byte bits 6-7 (64B segments -> distinct slots).
    const unsigned exw = (unsigned)(lane >> 4) << 6;
#pragma unroll
    for (int h = 0; h < 2; ++h) {
      __syncthreads();
      if ((w & 1) == h) {
#pragma unroll
        for (int mi = 0; mi < 8; ++mi)
#pragma unroll
          for (int ni = 0; ni < 4; ++ni) {
            const int colb = (wn + ni * 16 + lm) * 4;
#pragma unroll
            for (int r = 0; r < 4; ++r) {
              const unsigned ad = (unsigned)(mi * 16 + lr + r) * 1024 + colb;
              *(float*)((char*)smem + (ad ^ exw)) = acc[mi][ni][r];
            }
          }
      }
      __syncthreads();
#pragma unroll
      for (int s = 0; s < 16; ++s) {
        const int row = s * 8 + w;          // one full row per wave
        const int col = (lane & 63) * 4;
        const unsigned xr = (unsigned)((row >> 2) & 3) << 6;
        float4 v = *(const float4*)((char*)smem + (((unsigned)row * 1024 + col * 4) ^ xr));
        float4 bb = *(const float4*)(bias + n0 + col);
        v.x += bb.x; v.y += bb.y; v.z += bb.z; v.w += bb.w;
        *(float4*)((float*)Cout + (size_t)(m0 + h * 128 + row) * ldc + n0 + col) = v;
      }
    }
  }
}

// ---------------------------------------------------------------------------
// Stage 4: attention, one block (256 thr, 4 waves) per (b,h).
// XCD-chunked block swizzle (6144 = 8*768): adjacent heads (adjacent 128-B
// slices of the same qkv rows) land on the same XCD's L2.
// ---------------------------------------------------------------------------
__global__ __launch_bounds__(256) void attn_kernel(const bf16* __restrict__ qkv,
                                                   bf16* __restrict__ ctx) {
  constexpr int LDQ = 2304;
  constexpr int SQS = 72;   // sQ/sK row stride (64 cols + pad)
  constexpr int SPS = 136;  // sP/sVt row stride (128 cols + pad)
  __shared__ bf16 smem[27136];              // 54272 B
  bf16* sQ = smem;                          // [128][72]
  bf16* sK = smem + 128 * SQS;              // [128][72]
  bf16* sVt = smem + 2 * 128 * SQS;         // [64][136]  Vt[d][t] = V[t][d]
  bf16* sP = smem;                          // [128][136] aliases sQ+sK

  const int bh = (blockIdx.x & 7) * 768 + (blockIdx.x >> 3);
  const int b = bh / 12, h = bh % 12;
  const bf16* Qg = qkv + (size_t)b * 128 * LDQ + h * 64;
  const bf16* Kg = Qg + 768;
  const bf16* Vg = Qg + 1536;

  const int tid = threadIdx.x;
  // ---- load Q,K row-major; V transposed ----
  {
    int row = tid >> 1, half = tid & 1;
    const uint4* qsrc = (const uint4*)(Qg + (size_t)row * LDQ + half * 32);
    const uint4* ksrc = (const uint4*)(Kg + (size_t)row * LDQ + half * 32);
    const uint4* vsrc = (const uint4*)(Vg + (size_t)row * LDQ + half * 32);
    uint4* qdst = (uint4*)(sQ + row * SQS + half * 32);
    uint4* kdst = (uint4*)(sK + row * SQS + half * 32);
    uint4 vt[4];
    for (int i = 0; i < 4; ++i) {
      qdst[i] = qsrc[i];
      kdst[i] = ksrc[i];
      vt[i] = vsrc[i];
    }
    const bf16* tp = (const bf16*)vt;
    for (int d = 0; d < 32; ++d) sVt[(half * 32 + d) * SPS + row] = tp[d];
  }
  __syncthreads();

  const int lane = tid & 63;
  const int w = tid >> 6;      // wave handles rows w*32 .. w*32+31
  const int lm = lane & 15;
  const int kq = (lane >> 4) * 8;
  const int lr = (lane >> 4) * 4;

  // ---- S = Q K^T ----
  f32x4 sacc[2][8];
  for (int i = 0; i < 2; ++i)
    for (int j = 0; j < 8; ++j) sacc[i][j] = (f32x4){0.f, 0.f, 0.f, 0.f};
  for (int kk = 0; kk < 64; kk += 32) {
    bf16x8 aq[2], bk[8];
    for (int mi = 0; mi < 2; ++mi)
      aq[mi] = *(const bf16x8*)(sQ + (w * 32 + mi * 16 + lm) * SQS + kk + kq);
    for (int ni = 0; ni < 8; ++ni)
      bk[ni] = *(const bf16x8*)(sK + (ni * 16 + lm) * SQS + kk + kq);
    for (int mi = 0; mi < 2; ++mi)
      for (int ni = 0; ni < 8; ++ni)
        sacc[mi][ni] = MFMA16(aq[mi], bk[ni], sacc[mi][ni]);
  }

  // ---- causal softmax (scale=1/8) ----
  float inv[2][4];
  for (int mi = 0; mi < 2; ++mi) {
    for (int r = 0; r < 4; ++r) {
      int row = w * 32 + mi * 16 + lr + r;
      float vals[8];
      float mx = -INFINITY;
      for (int ni = 0; ni < 8; ++ni) {
        int col = ni * 16 + lm;
        float v = sacc[mi][ni][r] * 0.125f;
        if (col > row) v = -INFINITY;
        vals[ni] = v;
        mx = fmaxf(mx, v);
      }
      for (int off = 1; off < 16; off <<= 1) mx = fmaxf(mx, __shfl_xor(mx, off, 64));
      float sum = 0.f;
      for (int ni = 0; ni < 8; ++ni) {
        float p = __expf(vals[ni] - mx);  // exp(-inf)=0
        vals[ni] = p;
        sum += p;
      }
      for (int off = 1; off < 16; off <<= 1) sum += __shfl_xor(sum, off, 64);
      inv[mi][r] = 1.f / sum;
      for (int ni = 0; ni < 8; ++ni) sacc[mi][ni][r] = vals[ni];
    }
  }
  __syncthreads();  // all waves done reading sQ/sK before sP overwrites them

  // ---- write unnormalized P (bf16) to LDS ----
  for (int mi = 0; mi < 2; ++mi)
    for (int ni = 0; ni < 8; ++ni)
      for (int r = 0; r < 4; ++r) {
        int row = w * 32 + mi * 16 + lr + r;
        int col = ni * 16 + lm;
        sP[row * SPS + col] = (bf16)sacc[mi][ni][r];
      }
  __syncthreads();

  // ---- ctx = P * V ----
  f32x4 oacc[2][4];
  for (int i = 0; i < 2; ++i)
    for (int j = 0; j < 4; ++j) oacc[i][j] = (f32x4){0.f, 0.f, 0.f, 0.f};
  for (int kk = 0; kk < 128; kk += 32) {
    bf16x8 ap[2], bv[4];
    for (int mi = 0; mi < 2; ++mi)
      ap[mi] = *(const bf16x8*)(sP + (w * 32 + mi * 16 + lm) * SPS + kk + kq);
    for (int ci = 0; ci < 4; ++ci)
      bv[ci] = *(const bf16x8*)(sVt + (ci * 16 + lm) * SPS + kk + kq);
    for (int mi = 0; mi < 2; ++mi)
      for (int ci = 0; ci < 4; ++ci)
        oacc[mi][ci] = MFMA16(ap[mi], bv[ci], oacc[mi][ci]);
  }

  // ---- write ctx over the Q region ----
  bf16* Cg = ctx + (size_t)b * 128 * LDQ + h * 64;
  for (int mi = 0; mi < 2; ++mi)
    for (int ci = 0; ci < 4; ++ci)
      for (int r = 0; r < 4; ++r) {
        int row = w * 32 + mi * 16 + lr + r;
        int col = ci * 16 + lm;
        Cg[(size_t)row * LDQ + col] = (bf16)(oacc[mi][ci][r] * inv[mi][r]);
      }
}

// ---------------------------------------------------------------------------
extern "C" void kernel_launch(void* const* d_in, const int* in_sizes, int n_in,
                              void* d_out, int out_size, void* d_ws, size_t ws_size,
                              hipStream_t stream) {
  const float* x = (const float*)d_in[0];
  const float* Wq = (const float*)d_in[1];
  const float* Wk = (const float*)d_in[2];
  const float* Wv = (const float*)d_in[3];
  const float* Wo = (const float*)d_in[4];
  const float* bo = (const float*)d_in[5];
  float* out = (float*)d_out;

  constexpr int M = 512 * 128;      // 65536 tokens
  constexpr int D = 768;
  constexpr size_t XB_BYTES = (size_t)M * D * 2;            // 100663296
  constexpr size_t WQKV_BYTES = (size_t)3 * D * D * 2;      // 3538944
  constexpr size_t WOT_BYTES = (size_t)D * D * 2;           // 1179648

  char* ws = (char*)d_ws;
  bf16* xb = (bf16*)ws;
  bf16* wqkv = (bf16*)(ws + XB_BYTES);
  bf16* wot = (bf16*)(ws + XB_BYTES + WQKV_BYTES);
  bf16* qkv = (bf16*)(ws + XB_BYTES + WQKV_BYTES + WOT_BYTES);  // [M][2304]

  // 1) cast x
  cast_x_bf16<<<(M * D) / 1024, 256, 0, stream>>>(x, xb, M * D);
  // 2) weight transposes
  dim3 tb(32, 8);
  transpose_cast_w<<<dim3(24, 24), tb, 0, stream>>>(Wq, wqkv);
  transpose_cast_w<<<dim3(24, 24), tb, 0, stream>>>(Wk, wqkv + 768 * 768);
  transpose_cast_w<<<dim3(24, 24), tb, 0, stream>>>(Wv, wqkv + 2 * 768 * 768);
  transpose_cast_w<<<dim3(24, 24), tb, 0, stream>>>(Wo, wot);
  // 3) fused QKV GEMM: [65536 x 768] * [768 x 2304] -> bf16 [65536 x 2304]
  gemm256<false><<<dim3(2304), 512, 0, stream>>>(xb, 768, wqkv, 768, qkv, 2304,
                                                 nullptr, 768, 9);
  // 4) attention; ctx written in-place over Q region of qkv
  attn_kernel<<<512 * 12, 256, 0, stream>>>(qkv, qkv);
  // 5) output GEMM: ctx [65536 x 768] (lda=2304) * Wo -> fp32 out + bias
  gemm256<true><<<dim3(768), 512, 0, stream>>>(qkv, 2304, wot, 768, out, 768,
                                               bo, 768, 3);
}

// Round 3
// 767.010 us; speedup vs baseline: 1.1725x; 1.0284x over previous
//
#include <hip/hip_runtime.h>
#include <hip/hip_bf16.h>
#include <cstdint>
#include <math.h>

// ---------------------------------------------------------------------------
// MultiHeadAttention: B=512, T=128, D=768, H=12, hd=64. fp32 in/out,
// bf16 MFMA compute.
//
// Stages:
//   1) cast x (fp32) -> bf16                     [M=65536 x 768]
//   2) transpose+cast Wq/Wk/Wv -> Wqkv^T bf16    [2304 x 768], Wo^T [768 x 768]
//   3) GEMM qkv = x * Wqkv   (bf16 out)          [65536 x 2304]   gemm256
//   4) attention per (b,h); ctx overwrites Q region of qkv
//   5) GEMM out = ctx * Wo + bo (fp32 out)                        gemm256
//
// gemm256 (round 3): SINGLE barrier per phase. Round-2's double-barrier
// convoyed all 8 waves: reads (576-768 cyc LDS) and MFMA (620 cyc) strictly
// serialized -> 1530 cyc/phase, MfmaUtil 37%. With one barrier, waves drift
// up to one phase: early-finishing waves issue next-phase ds_reads + stage
// while late waves are still in MFMA -> the two pipes overlap.
//
// Race ledger (unchanged vmcnt chain, re-verified for 1 barrier):
//   - stage sched: ph1:SA(t1,1) ph2:SB(t2,0) ph3:SA(t2,0) ph4:SB(t2,1)+vm6
//                  ph5:SA(t2,1) ph6:SB(t3,0) ph7:SA(t3,0) ph8:SB(t3,1)+vm6
//   - visibility: vmcnt(6)@ph4 covers stages through cur-ph1; @ph8 through
//     cur-ph5; every phase's reads need only stages covered by the last
//     vmcnt-barrier before them (checked exhaustively, 1 phase slack).
//   - WAR on re-stage: STAGE(p) overwrites a region whose last ds_read was
//     issued at phase p-1 BEFORE barrier(p-1); the gload is issued after
//     barrier(p-1) + MFMA(p-1) (~620cy) + ~200cy flight vs ~120cy ds service
//     -> >=700 cyc margin. Wave drift is bounded by the barrier to <1 phase.
// ---------------------------------------------------------------------------

typedef __bf16 bf16;
typedef __bf16 bf16x8 __attribute__((ext_vector_type(8)));
typedef float f32x4 __attribute__((ext_vector_type(4)));

#define MFMA16(a, b, c) __builtin_amdgcn_mfma_f32_16x16x32_bf16((a), (b), (c), 0, 0, 0)

// async global->LDS, 16B per lane; LDS dest = wave-uniform base + lane*16
#define GLD_LDS16(gp, lp)                                                       \
  __builtin_amdgcn_global_load_lds(                                             \
      (const __attribute__((address_space(1))) void*)(gp),                      \
      (__attribute__((address_space(3))) void*)(lp), 16, 0, 0)

// ---------------------------------------------------------------------------
// Stage 1: fp32 -> bf16 cast, 4 elems/thread
// ---------------------------------------------------------------------------
__global__ __launch_bounds__(256) void cast_x_bf16(const float* __restrict__ in,
                                                   bf16* __restrict__ out, int n) {
  int i = (blockIdx.x * 256 + threadIdx.x) * 4;
  if (i < n) {
    float4 v = *(const float4*)(in + i);
    bf16 o[4] = {(bf16)v.x, (bf16)v.y, (bf16)v.z, (bf16)v.w};
    *(uint2*)(out + i) = *(const uint2*)o;
  }
}

// ---------------------------------------------------------------------------
// Stage 2: 768x768 transpose + cast: Out[n][k] = W[k][n]
// ---------------------------------------------------------------------------
__global__ __launch_bounds__(256) void transpose_cast_w(const float* __restrict__ W,
                                                        bf16* __restrict__ Out) {
  __shared__ float t[32][33];
  int bx = blockIdx.x * 32;  // k tile
  int by = blockIdx.y * 32;  // n tile
  int tx = threadIdx.x, ty = threadIdx.y;  // block (32,8)
  for (int i = 0; i < 32; i += 8)
    t[ty + i][tx] = W[(size_t)(bx + ty + i) * 768 + by + tx];
  __syncthreads();
  for (int i = 0; i < 32; i += 8)
    Out[(size_t)(by + ty + i) * 768 + bx + tx] = (bf16)t[tx][ty + i];
}

// ---------------------------------------------------------------------------
// Stages 3/5: bf16 GEMM, C[M,N] = A[M,K] * Bt[N,K]^T.
// Requires M%256==0, N%256==0, K%64==0, K/64 even and >=4, gridDim.x%8==0.
// ---------------------------------------------------------------------------
template <bool OUT_F32>
__global__ __launch_bounds__(512, 2) void gemm256(
    const bf16* __restrict__ A, int lda, const bf16* __restrict__ Bt, int ldb,
    void* __restrict__ Cout, int ldc, const float* __restrict__ bias, int K,
    int ntn) {
  // 2 buffers x 32768 elems; per buffer panels (8192 elems = 16 KiB each):
  //   A_k0 @0, A_k1 @8192, B_k0 @16384, B_k1 @24576
  __shared__ bf16 smem[2 * 32768];  // 131072 B

  const int tid = threadIdx.x;
  const int lane = tid & 63;
  const int w = tid >> 6;

  // T1: nt-major within A-panel groups, XCD-chunked bijective swizzle.
  const int nwg = gridDim.x;
  const int wg = (blockIdx.x & 7) * (nwg >> 3) + (blockIdx.x >> 3);
  const int m0 = (wg / ntn) * 256;
  const int n0 = (wg % ntn) * 256;

  // Staging constants: per-panel [256 rows][32 k], rows at 64 B stride,
  // swizzle phys_byte = logical ^ (((logical>>7)&3)<<4). Linear dest
  // d = s*8192B + tid*16B -> row = s*128 + (tid>>2), src col pre-swizzled.
  const int r0 = tid >> 2;
  const int c0 = ((((tid & 3) * 16) ^ (((tid >> 3) & 3) << 4)) >> 1);
  const bf16* As0 = A + (size_t)(m0 + r0) * lda + c0;
  const bf16* As1 = As0 + (size_t)128 * lda;
  const bf16* Bs0 = Bt + (size_t)(n0 + r0) * ldb + c0;
  const bf16* Bs1 = Bs0 + (size_t)128 * ldb;

  // Fragment-read constants (same swizzle; row bits 1-2 == lm bits 1-2).
  const int lm = lane & 15;
  const int kqs = ((lane >> 4) * 8) ^ (((lm >> 1) & 3) << 3);
  const int wm = (w & 1) * 128;   // wave M rows
  const int wn = (w >> 1) * 64;   // wave N cols
  const bf16* pA = smem + (wm + lm) * 32 + kqs;
  const bf16* pB = smem + 16384 + (wn + lm) * 32 + kqs;

  f32x4 acc[8][4];
#pragma unroll
  for (int i = 0; i < 8; ++i)
#pragma unroll
    for (int j = 0; j < 4; ++j) acc[i][j] = (f32x4){0.f, 0.f, 0.f, 0.f};

  bf16x8 af[4], bfr[4];

  const int NT = K >> 6;   // K-tiles of 64; 12 for K=768
  const int NH = NT >> 1;  // main iterations

  auto SA = [&](int t, int kh) {
    const int ko = t * 64 + kh * 32;
    const int lo = (t & 1) * 32768 + kh * 8192;
    GLD_LDS16(As0 + ko, smem + lo + w * 512);
    GLD_LDS16(As1 + ko, smem + lo + 4096 + w * 512);
  };
  auto SB = [&](int t, int kh) {
    const int ko = t * 64 + kh * 32;
    const int lo = (t & 1) * 32768 + 16384 + kh * 8192;
    GLD_LDS16(Bs0 + ko, smem + lo + w * 512);
    GLD_LDS16(Bs1 + ko, smem + lo + 4096 + w * 512);
  };
  auto RD = [&](int buf, int kh, int h, bool lb) {
    const bf16* a = pA + buf * 32768 + kh * 8192 + h * 2048;
#pragma unroll
    for (int j = 0; j < 4; ++j) af[j] = *(const bf16x8*)(a + j * 512);
    if (lb) {
      const bf16* b = pB + buf * 32768 + kh * 8192;
#pragma unroll
      for (int j = 0; j < 4; ++j) bfr[j] = *(const bf16x8*)(b + j * 512);
    }
  };
  // SINGLE barrier per phase: pin RD/STAGE above, then barrier, then wait
  // own ds_reads, then MFMA. vm = counted vmcnt before the barrier.
  auto BAR = [&](int vm) {
    __builtin_amdgcn_sched_barrier(0);
    if (vm == 6) asm volatile("s_waitcnt vmcnt(6)" ::: "memory");
    else if (vm == 0) asm volatile("s_waitcnt vmcnt(0)" ::: "memory");
    __builtin_amdgcn_s_barrier();
    asm volatile("s_waitcnt lgkmcnt(0)" ::: "memory");
    __builtin_amdgcn_sched_barrier(0);
  };
  auto MM = [&](int h) {
    __builtin_amdgcn_s_setprio(1);
#pragma unroll
    for (int j = 0; j < 4; ++j)
#pragma unroll
      for (int n = 0; n < 4; ++n)
        acc[h * 4 + j][n] = MFMA16(af[j], bfr[n], acc[h * 4 + j][n]);
    __builtin_amdgcn_s_setprio(0);
  };

  // ---- prologue: tile 0 fully + tile 1 minus A_k1 ----
  SB(0, 0); SA(0, 0); SB(0, 1); SA(0, 1);
  asm volatile("s_waitcnt vmcnt(4)" ::: "memory");
  SB(1, 0); SA(1, 0); SB(1, 1);
  asm volatile("s_waitcnt vmcnt(6)" ::: "memory");
  __builtin_amdgcn_s_barrier();
  __builtin_amdgcn_sched_barrier(0);

  // ---- main loop: iterations 0 .. NH-2 ----
  for (int i = 0; i < NH - 1; ++i) {
    const int t1 = 2 * i + 1, t2 = 2 * i + 2, t3 = 2 * i + 3;
    RD(0, 0, 0, true);  SA(t1, 1); BAR(-1); MM(0);  // ph1
    RD(0, 0, 1, false); SB(t2, 0); BAR(-1); MM(1);  // ph2
    RD(0, 1, 0, true);  SA(t2, 0); BAR(-1); MM(0);  // ph3
    RD(0, 1, 1, false); SB(t2, 1); BAR(6);  MM(1);  // ph4
    RD(1, 0, 0, true);  SA(t2, 1); BAR(-1); MM(0);  // ph5
    RD(1, 0, 1, false); SB(t3, 0); BAR(-1); MM(1);  // ph6
    RD(1, 1, 0, true);  SA(t3, 0); BAR(-1); MM(0);  // ph7
    RD(1, 1, 1, false); SB(t3, 1); BAR(6);  MM(1);  // ph8
  }
  // ---- last iteration (tiles NT-2, NT-1): only stage A_k1(NT-1) ----
  RD(0, 0, 0, true);  SA(NT - 1, 1); BAR(-1); MM(0);
  RD(0, 0, 1, false);                BAR(-1); MM(1);
  RD(0, 1, 0, true);                 BAR(-1); MM(0);
  RD(0, 1, 1, false);                BAR(0);  MM(1);
  RD(1, 0, 0, true);                 BAR(-1); MM(0);
  RD(1, 0, 1, false);                BAR(-1); MM(1);
  RD(1, 1, 0, true);                 BAR(-1); MM(0);
  RD(1, 1, 1, false);                BAR(-1); MM(1);

  __syncthreads();  // all staging landed (vmcnt(0) above), LDS free for epilogue

  // ---- vectorized epilogue via LDS ----
  // C/D layout: col=lane&15, row=(lane>>4)*4+reg  [m89/m91]
  const int lr = (lane >> 4) * 4;
  if constexpr (!OUT_F32) {
    const unsigned exw = (unsigned)(lane >> 4) << 5;
#pragma unroll
    for (int mi = 0; mi < 8; ++mi)
#pragma unroll
      for (int ni = 0; ni < 4; ++ni) {
        const int colb = (wn + ni * 16 + lm) * 2;
#pragma unroll
        for (int r = 0; r < 4; ++r) {
          const unsigned ad = (unsigned)(wm + mi * 16 + lr + r) * 512 + colb;
          *(bf16*)((char*)smem + (ad ^ exw)) = (bf16)acc[mi][ni][r];
        }
      }
    __syncthreads();
    const unsigned exr = (unsigned)((tid >> 7) & 3) << 5;
#pragma unroll
    for (int s = 0; s < 16; ++s) {
      const int e = s * 4096 + tid * 8;
      const int row = e >> 8, col = e & 255;
      uint4 v = *(const uint4*)((char*)smem + (((unsigned)row * 512 + col * 2) ^ exr));
      *(uint4*)((bf16*)Cout + (size_t)(m0 + row) * ldc + n0 + col) = v;
    }
  } else {
    const unsigned exw = (unsigned)(lane >> 4) << 6;
#pragma unroll
    for (int h = 0; h < 2; ++h) {
      __syncthreads();
      if ((w & 1) == h) {
#pragma unroll
        for (int mi = 0; mi < 8; ++mi)
#pragma unroll
          for (int ni = 0; ni < 4; ++ni) {
            const int colb = (wn + ni * 16 + lm) * 4;
#pragma unroll
            for (int r = 0; r < 4; ++r) {
              const unsigned ad = (unsigned)(mi * 16 + lr + r) * 1024 + colb;
              *(float*)((char*)smem + (ad ^ exw)) = acc[mi][ni][r];
            }
          }
      }
      __syncthreads();
#pragma unroll
      for (int s = 0; s < 16; ++s) {
        const int row = s * 8 + w;
        const int col = (lane & 63) * 4;
        const unsigned xr = (unsigned)((row >> 2) & 3) << 6;
        float4 v = *(const float4*)((char*)smem + (((unsigned)row * 1024 + col * 4) ^ xr));
        float4 bb = *(const float4*)(bias + n0 + col);
        v.x += bb.x; v.y += bb.y; v.z += bb.z; v.w += bb.w;
        *(float4*)((float*)Cout + (size_t)(m0 + h * 128 + row) * ldc + n0 + col) = v;
      }
    }
  }
}

// ---------------------------------------------------------------------------
// Stage 4: attention, one block (256 thr, 4 waves) per (b,h).
// Round 3: Q fragments loaded DIRECTLY global->VGPR (each Q element is read
// exactly once by exactly one wave -> LDS staging was pure overhead), hoisted
// above K/V staging so the load latency hides under it. LDS drops to
// 52,224 B -> 3 blocks/CU (3 x 52224 = 156672 <= 163840); launch_bounds
// (256,3) caps VGPRs to fit. XCD-chunked block swizzle kept.
// ---------------------------------------------------------------------------
__global__ __launch_bounds__(256, 3) void attn_kernel(const bf16* __restrict__ qkv,
                                                      bf16* __restrict__ ctx) {
  constexpr int LDQ = 2304;
  constexpr int SKS = 72;   // sK row stride (64 cols + pad)
  constexpr int SPS = 136;  // sP/sVt row stride (128 cols + pad)
  __shared__ bf16 smem[26112];              // 52224 B
  bf16* sK = smem;                          // [128][72]  (aliases sP front)
  bf16* sP = smem;                          // [128][136] = 17408 elems
  bf16* sVt = smem + 17408;                 // [64][136]  Vt[d][t] = V[t][d]

  const int bh = (blockIdx.x & 7) * 768 + (blockIdx.x >> 3);
  const int b = bh / 12, h = bh % 12;
  const bf16* Qg = qkv + (size_t)b * 128 * LDQ + h * 64;
  const bf16* Kg = Qg + 768;
  const bf16* Vg = Qg + 1536;

  const int tid = threadIdx.x;
  const int lane = tid & 63;
  const int w = tid >> 6;      // wave handles rows w*32 .. w*32+31
  const int lm = lane & 15;
  const int kq = (lane >> 4) * 8;
  const int lr = (lane >> 4) * 4;

  // ---- hoisted Q fragment loads (global -> VGPR), latency hidden by K/V
  // staging below. A-frag layout: lane lm = row, kq = k-offset.
  bf16x8 aq[2][2];
#pragma unroll
  for (int mi = 0; mi < 2; ++mi)
#pragma unroll
    for (int kk2 = 0; kk2 < 2; ++kk2)
      aq[mi][kk2] = *(const bf16x8*)(Qg + (size_t)(w * 32 + mi * 16 + lm) * LDQ +
                                     kk2 * 32 + kq);

  // ---- stage K row-major; V transposed ----
  {
    int row = tid >> 1, half = tid & 1;
    const uint4* ksrc = (const uint4*)(Kg + (size_t)row * LDQ + half * 32);
    const uint4* vsrc = (const uint4*)(Vg + (size_t)row * LDQ + half * 32);
    uint4* kdst = (uint4*)(sK + row * SKS + half * 32);
    uint4 vt[4];
    for (int i = 0; i < 4; ++i) {
      kdst[i] = ksrc[i];
      vt[i] = vsrc[i];
    }
    const bf16* tp = (const bf16*)vt;
    for (int d = 0; d < 32; ++d) sVt[(half * 32 + d) * SPS + row] = tp[d];
  }
  __syncthreads();

  // ---- S = Q K^T ----
  f32x4 sacc[2][8];
  for (int i = 0; i < 2; ++i)
    for (int j = 0; j < 8; ++j) sacc[i][j] = (f32x4){0.f, 0.f, 0.f, 0.f};
  for (int kk2 = 0; kk2 < 2; ++kk2) {
    bf16x8 bk[8];
    for (int ni = 0; ni < 8; ++ni)
      bk[ni] = *(const bf16x8*)(sK + (ni * 16 + lm) * SKS + kk2 * 32 + kq);
    for (int mi = 0; mi < 2; ++mi)
      for (int ni = 0; ni < 8; ++ni)
        sacc[mi][ni] = MFMA16(aq[mi][kk2], bk[ni], sacc[mi][ni]);
  }

  // ---- causal softmax (scale=1/8) ----
  float inv[2][4];
  for (int mi = 0; mi < 2; ++mi) {
    for (int r = 0; r < 4; ++r) {
      int row = w * 32 + mi * 16 + lr + r;
      float vals[8];
      float mx = -INFINITY;
      for (int ni = 0; ni < 8; ++ni) {
        int col = ni * 16 + lm;
        float v = sacc[mi][ni][r] * 0.125f;
        if (col > row) v = -INFINITY;
        vals[ni] = v;
        mx = fmaxf(mx, v);
      }
      for (int off = 1; off < 16; off <<= 1) mx = fmaxf(mx, __shfl_xor(mx, off, 64));
      float sum = 0.f;
      for (int ni = 0; ni < 8; ++ni) {
        float p = __expf(vals[ni] - mx);  // exp(-inf)=0
        vals[ni] = p;
        sum += p;
      }
      for (int off = 1; off < 16; off <<= 1) sum += __shfl_xor(sum, off, 64);
      inv[mi][r] = 1.f / sum;
      for (int ni = 0; ni < 8; ++ni) sacc[mi][ni][r] = vals[ni];
    }
  }
  __syncthreads();  // all waves done reading sK before sP overwrites it

  // ---- write unnormalized P (bf16) to LDS ----
  for (int mi = 0; mi < 2; ++mi)
    for (int ni = 0; ni < 8; ++ni)
      for (int r = 0; r < 4; ++r) {
        int row = w * 32 + mi * 16 + lr + r;
        int col = ni * 16 + lm;
        sP[row * SPS + col] = (bf16)sacc[mi][ni][r];
      }
  __syncthreads();

  // ---- ctx = P * V ----
  f32x4 oacc[2][4];
  for (int i = 0; i < 2; ++i)
    for (int j = 0; j < 4; ++j) oacc[i][j] = (f32x4){0.f, 0.f, 0.f, 0.f};
  for (int kk = 0; kk < 128; kk += 32) {
    bf16x8 ap[2], bv[4];
    for (int mi = 0; mi < 2; ++mi)
      ap[mi] = *(const bf16x8*)(sP + (w * 32 + mi * 16 + lm) * SPS + kk + kq);
    for (int ci = 0; ci < 4; ++ci)
      bv[ci] = *(const bf16x8*)(sVt + (ci * 16 + lm) * SPS + kk + kq);
    for (int mi = 0; mi < 2; ++mi)
      for (int ci = 0; ci < 4; ++ci)
        oacc[mi][ci] = MFMA16(ap[mi], bv[ci], oacc[mi][ci]);
  }

  // ---- write ctx over the Q region ----
  bf16* Cg = ctx + (size_t)b * 128 * LDQ + h * 64;
  for (int mi = 0; mi < 2; ++mi)
    for (int ci = 0; ci < 4; ++ci)
      for (int r = 0; r < 4; ++r) {
        int row = w * 32 + mi * 16 + lr + r;
        int col = ci * 16 + lm;
        Cg[(size_t)row * LDQ + col] = (bf16)(oacc[mi][ci][r] * inv[mi][r]);
      }
}

// ---------------------------------------------------------------------------
extern "C" void kernel_launch(void* const* d_in, const int* in_sizes, int n_in,
                              void* d_out, int out_size, void* d_ws, size_t ws_size,
                              hipStream_t stream) {
  const float* x = (const float*)d_in[0];
  const float* Wq = (const float*)d_in[1];
  const float* Wk = (const float*)d_in[2];
  const float* Wv = (const float*)d_in[3];
  const float* Wo = (const float*)d_in[4];
  const float* bo = (const float*)d_in[5];
  float* out = (float*)d_out;

  constexpr int M = 512 * 128;      // 65536 tokens
  constexpr int D = 768;
  constexpr size_t XB_BYTES = (size_t)M * D * 2;            // 100663296
  constexpr size_t WQKV_BYTES = (size_t)3 * D * D * 2;      // 3538944
  constexpr size_t WOT_BYTES = (size_t)D * D * 2;           // 1179648

  char* ws = (char*)d_ws;
  bf16* xb = (bf16*)ws;
  bf16* wqkv = (bf16*)(ws + XB_BYTES);
  bf16* wot = (bf16*)(ws + XB_BYTES + WQKV_BYTES);
  bf16* qkv = (bf16*)(ws + XB_BYTES + WQKV_BYTES + WOT_BYTES);  // [M][2304]

  // 1) cast x
  cast_x_bf16<<<(M * D) / 1024, 256, 0, stream>>>(x, xb, M * D);
  // 2) weight transposes
  dim3 tb(32, 8);
  transpose_cast_w<<<dim3(24, 24), tb, 0, stream>>>(Wq, wqkv);
  transpose_cast_w<<<dim3(24, 24), tb, 0, stream>>>(Wk, wqkv + 768 * 768);
  transpose_cast_w<<<dim3(24, 24), tb, 0, stream>>>(Wv, wqkv + 2 * 768 * 768);
  transpose_cast_w<<<dim3(24, 24), tb, 0, stream>>>(Wo, wot);
  // 3) fused QKV GEMM: [65536 x 768] * [768 x 2304] -> bf16 [65536 x 2304]
  gemm256<false><<<dim3(2304), 512, 0, stream>>>(xb, 768, wqkv, 768, qkv, 2304,
                                                 nullptr, 768, 9);
  // 4) attention; ctx written in-place over Q region of qkv
  attn_kernel<<<512 * 12, 256, 0, stream>>>(qkv, qkv);
  // 5) output GEMM: ctx [65536 x 768] (lda=2304) * Wo -> fp32 out + bias
  gemm256<true><<<dim3(768), 512, 0, stream>>>(qkv, 2304, wot, 768, out, 768,
                                               bo, 768, 3);
}